// Round 4
// baseline (9756.621 us; speedup 1.0000x reference)
//
#include <hip/hip_runtime.h>
#include <hip/hip_bf16.h>

// ---------------------------------------------------------------------------
// Problem constants
// ---------------------------------------------------------------------------
#define Bv 8
#define Sv 256
#define Hv 16
#define Dv 64
#define LR 0.1f
#define SCALE (2.0f / 8192.0f)   // dLoss/dpred scale: 2/(B*H*D)

using bf16x8 = __attribute__((ext_vector_type(8))) short;
using bf16x4 = __attribute__((ext_vector_type(4))) short;
using f32x4  = __attribute__((ext_vector_type(4))) float;
using u32x4  = __attribute__((ext_vector_type(4))) unsigned;
#define MFMA16(A, B, C) __builtin_amdgcn_mfma_f32_16x16x32_bf16(A, B, C, 0, 0, 0)

// ---------------------------------------------------------------------------
// Per-head LDS layout. ushort offsets unless noted. Pitch-136 planes carry
// hi[64]|lo[64]|pad[8]. W2R is hi-only pitch 72. T-arrays are packed u32
// [dim][8]: dword = hi | lo<<16.
// ---------------------------------------------------------------------------
constexpr int U_W1T = 0;         // [f][d] 64x136
constexpr int U_W2T = 8704;      // [d][f] 64x136
constexpr int U_W2R = 17408;     // [f][d] 64x72 hi-only
constexpr int U_Kp  = 22016;     // 16x136
constexpr int U_Hp  = 24192;
constexpr int U_DPp = 26368;
constexpr int U_KT  = 28544;     // u32[64][8] (1024 ushorts each)
constexpr int U_HT  = 29568;
constexpr int U_DOT = 30592;
constexpr int U_DAT = 31616;
// float offsets (from head float base)
constexpr int F_O    = 16320;    // o / dz [8][68]
constexpr int F_XH   = 16864;
constexpr int F_GD   = 17408;
constexpr int F_TG   = 17952;
constexpr int F_B1   = 18496;
constexpr int F_B2   = 18560;
constexpr int F_LG   = 18624;
constexpr int F_LB   = 18688;
constexpr int F_LBV  = 18752;
constexpr int F_TGm  = 18816;
constexpr int F_TBm  = 18880;
constexpr int F_RSTD = 18944;    // [8]
constexpr int F_PS1  = 18952;    // [8][4]
constexpr int F_PS2  = 18984;    // [8][4]
constexpr int HEAD_F = 19016;
constexpr int HEAD_U = 38032;
constexpr int LDS_BYTES = 2 * HEAD_U * 2;   // 152128 B

// ---------------------------------------------------------------------------
// Helpers
// ---------------------------------------------------------------------------
__device__ __forceinline__ short bf_rn(float v) {
    unsigned u = __float_as_uint(v);
    unsigned r = u + 0x7fffu + ((u >> 16) & 1u);
    return (short)(r >> 16);
}
__device__ __forceinline__ void cvt1(float v, short &hi, short &lo) {
    hi = bf_rn(v);
    float hf = __uint_as_float(((unsigned)(unsigned short)hi) << 16);
    lo = bf_rn(v - hf);
}
__device__ __forceinline__ float bf2f(short u) {
    return __uint_as_float(((unsigned)(unsigned short)u) << 16);
}
__device__ __forceinline__ unsigned pkbf(float a, float b) {
    __hip_bfloat162 r = __float22bfloat162_rn(make_float2(a, b));
    unsigned u;
    __builtin_memcpy(&u, &r, sizeof(u));
    return u;
}
// hp = bf(a)|bf(b)<<16 ; lp = residual pair (RTNE split)
__device__ __forceinline__ void cvt2pk(float a, float b, unsigned &hp, unsigned &lp) {
    hp = pkbf(a, b);
    float ha = __uint_as_float(hp << 16);
    float hb = __uint_as_float(hp & 0xffff0000u);
    lp = pkbf(a - ha, b - hb);
}
__device__ __forceinline__ bf16x8 mk8(unsigned a, unsigned b, unsigned c, unsigned d) {
    union { unsigned u[4]; bf16x8 v; } x;
    x.u[0] = a; x.u[1] = b; x.u[2] = c; x.u[3] = d;
    return x.v;
}
__device__ __forceinline__ float red16(float v) {
    v += __shfl_xor(v, 1);
    v += __shfl_xor(v, 2);
    v += __shfl_xor(v, 4);
    v += __shfl_xor(v, 8);
    return v;
}
__device__ __forceinline__ float red32(float v) {
    v += __shfl_xor(v, 1); v += __shfl_xor(v, 2); v += __shfl_xor(v, 4);
    v += __shfl_xor(v, 8); v += __shfl_xor(v, 16);
    return v;
}
__device__ __forceinline__ float fast_tanh(float u) {
    u = fminf(fmaxf(u, -10.f), 10.f);
    float e = __expf(2.0f * u);
    return (e - 1.0f) / (e + 1.0f);
}
__device__ __forceinline__ void gelu_both(float x, float &g, float &dg) {
    const float C0 = 0.7978845608028654f, A0 = 0.044715f;
    float x2 = x * x;
    float u = C0 * x * (1.0f + A0 * x2);
    float t = fast_tanh(u);
    g = 0.5f * x * (1.0f + t);
    float du = C0 * (1.0f + 3.0f * A0 * x2);
    dg = 0.5f * (1.0f + t) + 0.5f * x * (1.0f - t * t) * du;
}
__device__ __forceinline__ float gelu_f(float x) {
    const float C0 = 0.7978845608028654f, A0 = 0.044715f;
    float u = C0 * x * (1.0f + A0 * x * x);
    return 0.5f * x * (1.0f + fast_tanh(u));
}

// ---- MFMA micro-kernels (16x64 @ 64x64, wave w owns col tile 16w) ---------
__device__ __forceinline__ f32x4 mm_ll(const unsigned short *Ap,
                                       const unsigned short *Bp,
                                       int w, int c, int q) {
    const unsigned short *ar = Ap + c * 136 + 8 * q;
    const unsigned short *br = Bp + (16 * w + c) * 136 + 8 * q;
    bf16x8 ah0 = *(const bf16x8 *)ar, al0 = *(const bf16x8 *)(ar + 64);
    bf16x8 ah1 = *(const bf16x8 *)(ar + 32), al1 = *(const bf16x8 *)(ar + 96);
    bf16x8 bh0 = *(const bf16x8 *)br, bl0 = *(const bf16x8 *)(br + 64);
    bf16x8 bh1 = *(const bf16x8 *)(br + 32), bl1 = *(const bf16x8 *)(br + 96);
    f32x4 x0 = {0.f, 0.f, 0.f, 0.f}, x1 = {0.f, 0.f, 0.f, 0.f};
    x0 = MFMA16(ah0, bh0, x0); x1 = MFMA16(ah1, bh1, x1);
    x0 = MFMA16(al0, bh0, x0); x1 = MFMA16(al1, bh1, x1);
    x0 = MFMA16(ah0, bl0, x0); x1 = MFMA16(ah1, bl1, x1);
    x0 = MFMA16(al0, bl0, x0); x1 = MFMA16(al1, bl1, x1);
    return x0 + x1;
}
__device__ __forceinline__ f32x4 mm_lr(const unsigned short *Ap,
                                       const bf16x8 *Bf, int c, int q) {
    const unsigned short *ar = Ap + c * 136 + 8 * q;
    bf16x8 ah0 = *(const bf16x8 *)ar, al0 = *(const bf16x8 *)(ar + 64);
    bf16x8 ah1 = *(const bf16x8 *)(ar + 32), al1 = *(const bf16x8 *)(ar + 96);
    f32x4 x0 = {0.f, 0.f, 0.f, 0.f}, x1 = {0.f, 0.f, 0.f, 0.f};
    x0 = MFMA16(ah0, Bf[0], x0); x1 = MFMA16(ah1, Bf[2], x1);
    x0 = MFMA16(al0, Bf[0], x0); x1 = MFMA16(al1, Bf[2], x1);
    x0 = MFMA16(ah0, Bf[1], x0); x1 = MFMA16(ah1, Bf[3], x1);
    x0 = MFMA16(al0, Bf[1], x0); x1 = MFMA16(al1, Bf[3], x1);
    return x0 + x1;
}
__device__ __forceinline__ f32x4 mm_rr(const bf16x8 *Af, const bf16x8 *Bf) {
    f32x4 x0 = {0.f, 0.f, 0.f, 0.f}, x1 = {0.f, 0.f, 0.f, 0.f};
    x0 = MFMA16(Af[0], Bf[0], x0); x1 = MFMA16(Af[2], Bf[2], x1);
    x0 = MFMA16(Af[1], Bf[0], x0); x1 = MFMA16(Af[3], Bf[2], x1);
    x0 = MFMA16(Af[0], Bf[1], x0); x1 = MFMA16(Af[2], Bf[3], x1);
    x0 = MFMA16(Af[1], Bf[1], x0); x1 = MFMA16(Af[3], Bf[3], x1);
    return x0 + x1;
}
__device__ __forceinline__ f32x4 mm_rh(const bf16x8 *Af,
                                       const unsigned short *BpHi,
                                       int w, int c, int q) {
    const unsigned short *br = BpHi + (16 * w + c) * 72 + 8 * q;
    bf16x8 bh0 = *(const bf16x8 *)br, bh1 = *(const bf16x8 *)(br + 32);
    f32x4 x0 = {0.f, 0.f, 0.f, 0.f}, x1 = {0.f, 0.f, 0.f, 0.f};
    x0 = MFMA16(Af[0], bh0, x0); x1 = MFMA16(Af[2], bh1, x1);
    x0 = MFMA16(Af[1], bh0, x0); x1 = MFMA16(Af[3], bh1, x1);
    return x0 + x1;
}

// W(col 16w+c) -= LR * X^T@Y ; X,Y packed-u32 T arrays [64][8].
__device__ __forceinline__ void updW(const unsigned *XT, const unsigned *YT,
                                     unsigned short *WT, unsigned short *WRh,
                                     int w, int c, int q) {
    bf16x8 zf = {0, 0, 0, 0, 0, 0, 0, 0};
    bf16x8 bh = zf, bl = zf;
    if (q == 0) {
        u32x4 y0 = *(const u32x4 *)&YT[(16 * w + c) * 8];
        u32x4 y1 = *(const u32x4 *)&YT[(16 * w + c) * 8 + 4];
#pragma unroll
        for (int j = 0; j < 4; ++j) {
            bh[j] = (short)(y0[j] & 0xffffu); bl[j] = (short)(y0[j] >> 16);
            bh[4 + j] = (short)(y1[j] & 0xffffu); bl[4 + j] = (short)(y1[j] >> 16);
        }
    }
#pragma unroll
    for (int mt = 0; mt < 4; ++mt) {
        bf16x8 ah = zf, al = zf;
        if (q == 0) {
            u32x4 x0 = *(const u32x4 *)&XT[(16 * mt + c) * 8];
            u32x4 x1 = *(const u32x4 *)&XT[(16 * mt + c) * 8 + 4];
#pragma unroll
            for (int j = 0; j < 4; ++j) {
                ah[j] = (short)(x0[j] & 0xffffu); al[j] = (short)(x0[j] >> 16);
                ah[4 + j] = (short)(x1[j] & 0xffffu); al[4 + j] = (short)(x1[j] >> 16);
            }
        }
        f32x4 g = {0.f, 0.f, 0.f, 0.f};
        g = MFMA16(ah, bh, g);
        g = MFMA16(al, bh, g);
        g = MFMA16(ah, bl, g);
        unsigned short *ph = &WT[(16 * w + c) * 136 + 16 * mt + 4 * q];
        unsigned short *pl = ph + 64;
        bf16x4 oh = *(bf16x4 *)ph, ol = *(bf16x4 *)pl, nh, nl;
#pragma unroll
        for (int r = 0; r < 4; ++r) {
            float wv = bf2f(oh[r]) + bf2f(ol[r]) - LR * g[r];
            short hh, ll;
            cvt1(wv, hh, ll);
            nh[r] = hh; nl[r] = ll;
            if (WRh) WRh[(16 * mt + 4 * q + r) * 72 + 16 * w + c] = (unsigned short)hh;
        }
        *(bf16x4 *)ph = nh;
        *(bf16x4 *)pl = nl;
    }
}

// ---------------------------------------------------------------------------
// TTT scan: 8 blocks x 512 threads; 2 heads/block (head-half = tid>>8)
// ---------------------------------------------------------------------------
__global__ __launch_bounds__(512) void ttt_scan(
    const float *__restrict__ q_g, const float *__restrict__ k_g,
    const float *__restrict__ v_g, float *__restrict__ out_g,
    const float *__restrict__ fw_w1, const float *__restrict__ fw_b1,
    const float *__restrict__ fw_w2, const float *__restrict__ fw_b2,
    const float *__restrict__ fw_lng, const float *__restrict__ fw_lnb,
    const float *__restrict__ loss_w, const float *__restrict__ loss_bv,
    const float *__restrict__ ttt_gv, const float *__restrict__ ttt_bv) {
    extern __shared__ char smem[];
    const int tid = threadIdx.x;
    const int hb = tid >> 8;
    const int h = blockIdx.x * 2 + hb;
    const int tid8 = tid & 255;
    const int w = tid8 >> 6, lane = tid & 63, c = lane & 15, q = lane >> 4;

    unsigned short *ub = (unsigned short *)smem + hb * HEAD_U;
    float *fbp = (float *)smem + hb * HEAD_F;
    unsigned short *W1T = ub + U_W1T, *W2T = ub + U_W2T, *W2R = ub + U_W2R;
    unsigned short *Kp = ub + U_Kp, *Hp = ub + U_Hp, *DPp = ub + U_DPp;
    unsigned *KT32 = (unsigned *)(ub + U_KT), *HT32 = (unsigned *)(ub + U_HT);
    unsigned *DOT32 = (unsigned *)(ub + U_DOT), *DAT32 = (unsigned *)(ub + U_DAT);
    float *o_s = fbp + F_O, *xh_s = fbp + F_XH, *gd_s = fbp + F_GD;
    float *tg_s = fbp + F_TG;
    float *b1_s = fbp + F_B1, *b2_s = fbp + F_B2, *lg_s = fbp + F_LG;
    float *lb_s = fbp + F_LB, *Lb_s = fbp + F_LBV;
    float *tG_s = fbp + F_TGm, *tB_s = fbp + F_TBm;
    float *rstd_s = fbp + F_RSTD, *ps1 = fbp + F_PS1, *ps2 = fbp + F_PS2;

    // ---- init weights into planes
    for (int i = tid8; i < 4096; i += 256) {
        int r = i >> 6, cc = i & 63;
        short hi, lo;
        cvt1(fw_w1[h * 4096 + i], hi, lo);          // W1 [d=r][f=cc]
        W1T[cc * 136 + r] = (unsigned short)hi;
        W1T[cc * 136 + 64 + r] = (unsigned short)lo;
        cvt1(fw_w2[h * 4096 + i], hi, lo);          // W2 [f=r][d=cc]
        W2T[cc * 136 + r] = (unsigned short)hi;
        W2T[cc * 136 + 64 + r] = (unsigned short)lo;
        W2R[r * 72 + cc] = (unsigned short)hi;      // hi-only
    }
    // zero pad rows 8..15 of Kp/Hp/DPp
    for (int i = tid8; i < 3 * 8 * 136; i += 256) {
        int a = i / (8 * 136), rem = i % (8 * 136);
        int r = 8 + rem / 136, u = rem % 136;
        (a == 0 ? Kp : a == 1 ? Hp : DPp)[r * 136 + u] = 0;
    }
    if (tid8 < 64) {
        b1_s[tid8] = fw_b1[h * 64 + tid8];
        b2_s[tid8] = fw_b2[h * 64 + tid8];
        lg_s[tid8] = fw_lng[h * 64 + tid8];
        lb_s[tid8] = fw_lnb[h * 64 + tid8];
        Lb_s[tid8] = loss_bv[tid8];
        tG_s[tid8] = ttt_gv[h * 64 + tid8];
        tB_s[tid8] = ttt_bv[h * 64 + tid8];
    }
    // ---- Lw fragments in registers (constant for whole kernel)
    bf16x8 LwTf[4], LwRf[4];
    {
        float tv[8];
        unsigned hp0, lp0, hp1, lp1, hp2, lp2, hp3, lp3;
        // LwT chain0: k=8q+j -> Lw[8q+j][16w+c]
#pragma unroll
        for (int j = 0; j < 8; ++j) tv[j] = loss_w[(8 * q + j) * 64 + 16 * w + c];
        cvt2pk(tv[0], tv[1], hp0, lp0); cvt2pk(tv[2], tv[3], hp1, lp1);
        cvt2pk(tv[4], tv[5], hp2, lp2); cvt2pk(tv[6], tv[7], hp3, lp3);
        LwTf[0] = mk8(hp0, hp1, hp2, hp3); LwTf[1] = mk8(lp0, lp1, lp2, lp3);
#pragma unroll
        for (int j = 0; j < 8; ++j) tv[j] = loss_w[(32 + 8 * q + j) * 64 + 16 * w + c];
        cvt2pk(tv[0], tv[1], hp0, lp0); cvt2pk(tv[2], tv[3], hp1, lp1);
        cvt2pk(tv[4], tv[5], hp2, lp2); cvt2pk(tv[6], tv[7], hp3, lp3);
        LwTf[2] = mk8(hp0, hp1, hp2, hp3); LwTf[3] = mk8(lp0, lp1, lp2, lp3);
        // LwR chain0: k=8q+j -> Lw[16w+c][8q+j] (contiguous)
        float4 ra = *(const float4 *)&loss_w[(16 * w + c) * 64 + 8 * q];
        float4 rb = *(const float4 *)&loss_w[(16 * w + c) * 64 + 8 * q + 4];
        cvt2pk(ra.x, ra.y, hp0, lp0); cvt2pk(ra.z, ra.w, hp1, lp1);
        cvt2pk(rb.x, rb.y, hp2, lp2); cvt2pk(rb.z, rb.w, hp3, lp3);
        LwRf[0] = mk8(hp0, hp1, hp2, hp3); LwRf[1] = mk8(lp0, lp1, lp2, lp3);
        ra = *(const float4 *)&loss_w[(16 * w + c) * 64 + 32 + 8 * q];
        rb = *(const float4 *)&loss_w[(16 * w + c) * 64 + 32 + 8 * q + 4];
        cvt2pk(ra.x, ra.y, hp0, lp0); cvt2pk(ra.z, ra.w, hp1, lp1);
        cvt2pk(rb.x, rb.y, hp2, lp2); cvt2pk(rb.z, rb.w, hp3, lp3);
        LwRf[2] = mk8(hp0, hp1, hp2, hp3); LwRf[3] = mk8(lp0, lp1, lp2, lp3);
    }
    __syncthreads();

    const int bb = tid8 >> 5, j0 = (tid8 & 31) * 2;
    float2 pk, pv, pq;
    {
        int idx = ((bb * Sv + 0) * Hv + h) * Dv + j0;
        pk = *(const float2 *)&k_g[idx];
        pv = *(const float2 *)&v_g[idx];
        pq = *(const float2 *)&q_g[idx];
    }

#pragma unroll 1
    for (int t = 0; t < Sv; ++t) {
        // ---- prologue: stage k planes + KT32 + tg
        {
            unsigned hp, lp;
            cvt2pk(pk.x, pk.y, hp, lp);
            *(unsigned *)&Kp[bb * 136 + j0] = hp;
            *(unsigned *)&Kp[bb * 136 + 64 + j0] = lp;
            KT32[j0 * 8 + bb] = (hp & 0xffffu) | (lp << 16);
            KT32[(j0 + 1) * 8 + bb] = (hp >> 16) | (lp & 0xffff0000u);
            tg_s[bb * 68 + j0] = pv.x - pk.x;
            tg_s[bb * 68 + j0 + 1] = pv.y - pk.y;
        }
        __syncthreads();

#pragma unroll 1
        for (int step = 0; step < 5; ++step) {
            // ---- F1: h = gelu(k@W1 + b1)
            f32x4 acc = mm_ll(Kp, W1T, w, c, q);
            if (q < 2) {
                float bias = b1_s[16 * w + c];
                float g[4], dg[4];
#pragma unroll
                for (int r = 0; r < 4; ++r) gelu_both(acc[r] + bias, g[r], dg[r]);
                unsigned hp0, lp0, hp1, lp1;
                cvt2pk(g[0], g[1], hp0, lp0);
                cvt2pk(g[2], g[3], hp1, lp1);
                int col = 16 * w + c;
                Hp[(4 * q + 0) * 136 + col] = (unsigned short)(hp0 & 0xffffu);
                Hp[(4 * q + 1) * 136 + col] = (unsigned short)(hp0 >> 16);
                Hp[(4 * q + 2) * 136 + col] = (unsigned short)(hp1 & 0xffffu);
                Hp[(4 * q + 3) * 136 + col] = (unsigned short)(hp1 >> 16);
                Hp[(4 * q + 0) * 136 + 64 + col] = (unsigned short)(lp0 & 0xffffu);
                Hp[(4 * q + 1) * 136 + 64 + col] = (unsigned short)(lp0 >> 16);
                Hp[(4 * q + 2) * 136 + 64 + col] = (unsigned short)(lp1 & 0xffffu);
                Hp[(4 * q + 3) * 136 + 64 + col] = (unsigned short)(lp1 >> 16);
                u32x4 ht;
                ht[0] = (hp0 & 0xffffu) | (lp0 << 16);
                ht[1] = (hp0 >> 16) | (lp0 & 0xffff0000u);
                ht[2] = (hp1 & 0xffffu) | (lp1 << 16);
                ht[3] = (hp1 >> 16) | (lp1 & 0xffff0000u);
                *(u32x4 *)&HT32[col * 8 + 4 * q] = ht;
#pragma unroll
                for (int r = 0; r < 4; ++r) gd_s[(4 * q + r) * 68 + col] = dg[r];
            }
            __syncthreads();
            // ---- F2: o = h@W2 + b2 ; partial row sums
            acc = mm_ll(Hp, W2T, w, c, q);
            if (q < 2) {
                float bias = b2_s[16 * w + c];
#pragma unroll
                for (int r = 0; r < 4; ++r) {
                    float ov = acc[r] + bias;
                    o_s[(4 * q + r) * 68 + 16 * w + c] = ov;
                    float sv = red16(ov), sq = red16(ov * ov);
                    if (c == 0) {
                        ps1[(4 * q + r) * 4 + w] = sv;
                        ps2[(4 * q + r) * 4 + w] = sq;
                    }
                }
            }
            __syncthreads();

            if (step < 4) {
                // ---- F3: prologue LN-apply (z frags in regs), mm vs LwT regs
                bf16x8 zfr[4] = {{0,0,0,0,0,0,0,0},{0,0,0,0,0,0,0,0},
                                 {0,0,0,0,0,0,0,0},{0,0,0,0,0,0,0,0}};
                if (c < 8) {
                    float4 p1 = *(float4 *)&ps1[c * 4];
                    float4 p2 = *(float4 *)&ps2[c * 4];
                    float mu = (p1.x + p1.y + p1.z + p1.w) * (1.f / 64.f);
                    float ms = (p2.x + p2.y + p2.z + p2.w) * (1.f / 64.f);
                    float rs = rsqrtf(ms - mu * mu + 1e-5f);
                    float4 oa = *(float4 *)&o_s[c * 68 + 8 * q];
                    float4 ob = *(float4 *)&o_s[c * 68 + 8 * q + 4];
                    float4 oc = *(float4 *)&o_s[c * 68 + 32 + 8 * q];
                    float4 od = *(float4 *)&o_s[c * 68 + 32 + 8 * q + 4];
                    float4 ga = *(float4 *)&lg_s[8 * q];
                    float4 gb = *(float4 *)&lg_s[8 * q + 4];
                    float4 gc = *(float4 *)&lg_s[32 + 8 * q];
                    float4 ge = *(float4 *)&lg_s[32 + 8 * q + 4];
                    float4 ba = *(float4 *)&lb_s[8 * q];
                    float4 bbv = *(float4 *)&lb_s[8 * q + 4];
                    float4 bc = *(float4 *)&lb_s[32 + 8 * q];
                    float4 be = *(float4 *)&lb_s[32 + 8 * q + 4];
                    float xh[16], z[16];
                    float ov[16] = {oa.x, oa.y, oa.z, oa.w, ob.x, ob.y, ob.z, ob.w,
                                    oc.x, oc.y, oc.z, oc.w, od.x, od.y, od.z, od.w};
                    float gv[16] = {ga.x, ga.y, ga.z, ga.w, gb.x, gb.y, gb.z, gb.w,
                                    gc.x, gc.y, gc.z, gc.w, ge.x, ge.y, ge.z, ge.w};
                    float bv[16] = {ba.x, ba.y, ba.z, ba.w, bbv.x, bbv.y, bbv.z, bbv.w,
                                    bc.x, bc.y, bc.z, bc.w, be.x, be.y, be.z, be.w};
#pragma unroll
                    for (int j = 0; j < 16; ++j) {
                        xh[j] = (ov[j] - mu) * rs;
                        z[j] = xh[j] * gv[j] + bv[j];
                    }
                    unsigned hp[8], lp[8];
#pragma unroll
                    for (int j = 0; j < 8; ++j) cvt2pk(z[2 * j], z[2 * j + 1], hp[j], lp[j]);
                    zfr[0] = mk8(hp[0], hp[1], hp[2], hp[3]);
                    zfr[1] = mk8(lp[0], lp[1], lp[2], lp[3]);
                    zfr[2] = mk8(hp[4], hp[5], hp[6], hp[7]);
                    zfr[3] = mk8(lp[4], lp[5], lp[6], lp[7]);
                    if (w == 0) {
                        *(float4 *)&xh_s[c * 68 + 8 * q] = make_float4(xh[0], xh[1], xh[2], xh[3]);
                        *(float4 *)&xh_s[c * 68 + 8 * q + 4] = make_float4(xh[4], xh[5], xh[6], xh[7]);
                        *(float4 *)&xh_s[c * 68 + 32 + 8 * q] = make_float4(xh[8], xh[9], xh[10], xh[11]);
                        *(float4 *)&xh_s[c * 68 + 32 + 8 * q + 4] = make_float4(xh[12], xh[13], xh[14], xh[15]);
                        if (q == 0) rstd_s[c] = rs;
                    }
                }
                acc = mm_rr(zfr, LwTf);
                if (q < 2) {
                    int col = 16 * w + c;
                    float dp[4];
#pragma unroll
                    for (int r = 0; r < 4; ++r)
                        dp[r] = (acc[r] + Lb_s[col] - tg_s[(4 * q + r) * 68 + col]) * SCALE;
                    unsigned hp0, lp0, hp1, lp1;
                    cvt2pk(dp[0], dp[1], hp0, lp0);
                    cvt2pk(dp[2], dp[3], hp1, lp1);
                    DPp[(4 * q + 0) * 136 + col] = (unsigned short)(hp0 & 0xffffu);
                    DPp[(4 * q + 1) * 136 + col] = (unsigned short)(hp0 >> 16);
                    DPp[(4 * q + 2) * 136 + col] = (unsigned short)(hp1 & 0xffffu);
                    DPp[(4 * q + 3) * 136 + col] = (unsigned short)(hp1 >> 16);
                    DPp[(4 * q + 0) * 136 + 64 + col] = (unsigned short)(lp0 & 0xffffu);
                    DPp[(4 * q + 1) * 136 + 64 + col] = (unsigned short)(lp0 >> 16);
                    DPp[(4 * q + 2) * 136 + 64 + col] = (unsigned short)(lp1 & 0xffffu);
                    DPp[(4 * q + 3) * 136 + 64 + col] = (unsigned short)(lp1 >> 16);
                }
                __syncthreads();
                // ---- B1: dz = dp @ Lw^T ; LNb partial sums
                acc = mm_lr(DPp, LwRf, c, q);
                if (q < 2) {
                    float lgc = lg_s[16 * w + c];
#pragma unroll
                    for (int r = 0; r < 4; ++r) {
                        float dz = acc[r];
                        o_s[(4 * q + r) * 68 + 16 * w + c] = dz;
                        float xv = xh_s[(4 * q + r) * 68 + 16 * w + c];
                        float d1 = dz * lgc;
                        float s1 = red16(d1), s2 = red16(d1 * xv);
                        if (c == 0) {
                            ps1[(4 * q + r) * 4 + w] = s1;
                            ps2[(4 * q + r) * 4 + w] = s2;
                        }
                    }
                }
                __syncthreads();
                // ---- B2: prologue LNb-apply (do frags in regs), mm vs W2R-hi
                bf16x8 dofr[4] = {{0,0,0,0,0,0,0,0},{0,0,0,0,0,0,0,0},
                                  {0,0,0,0,0,0,0,0},{0,0,0,0,0,0,0,0}};
                if (c < 8) {
                    float4 p1 = *(float4 *)&ps1[c * 4];
                    float4 p2 = *(float4 *)&ps2[c * 4];
                    float S1 = (p1.x + p1.y + p1.z + p1.w) * (1.f / 64.f);
                    float S2 = (p2.x + p2.y + p2.z + p2.w) * (1.f / 64.f);
                    float rs = rstd_s[c];
                    float4 za = *(float4 *)&o_s[c * 68 + 8 * q];
                    float4 zb = *(float4 *)&o_s[c * 68 + 8 * q + 4];
                    float4 zc = *(float4 *)&o_s[c * 68 + 32 + 8 * q];
                    float4 zd = *(float4 *)&o_s[c * 68 + 32 + 8 * q + 4];
                    float4 xa = *(float4 *)&xh_s[c * 68 + 8 * q];
                    float4 xb = *(float4 *)&xh_s[c * 68 + 8 * q + 4];
                    float4 xc = *(float4 *)&xh_s[c * 68 + 32 + 8 * q];
                    float4 xd = *(float4 *)&xh_s[c * 68 + 32 + 8 * q + 4];
                    float4 ga = *(float4 *)&lg_s[8 * q];
                    float4 gb = *(float4 *)&lg_s[8 * q + 4];
                    float4 gc = *(float4 *)&lg_s[32 + 8 * q];
                    float4 ge = *(float4 *)&lg_s[32 + 8 * q + 4];
                    float dzv[16] = {za.x, za.y, za.z, za.w, zb.x, zb.y, zb.z, zb.w,
                                     zc.x, zc.y, zc.z, zc.w, zd.x, zd.y, zd.z, zd.w};
                    float xv[16] = {xa.x, xa.y, xa.z, xa.w, xb.x, xb.y, xb.z, xb.w,
                                    xc.x, xc.y, xc.z, xc.w, xd.x, xd.y, xd.z, xd.w};
                    float gv[16] = {ga.x, ga.y, ga.z, ga.w, gb.x, gb.y, gb.z, gb.w,
                                    gc.x, gc.y, gc.z, gc.w, ge.x, ge.y, ge.z, ge.w};
                    float dov[16];
#pragma unroll
                    for (int j = 0; j < 16; ++j)
                        dov[j] = rs * (dzv[j] * gv[j] - S1 - xv[j] * S2);
                    unsigned hp[8], lp[8];
#pragma unroll
                    for (int j = 0; j < 8; ++j) cvt2pk(dov[2 * j], dov[2 * j + 1], hp[j], lp[j]);
                    dofr[0] = mk8(hp[0], hp[1], hp[2], hp[3]);
                    dofr[1] = mk8(lp[0], lp[1], lp[2], lp[3]);
                    dofr[2] = mk8(hp[4], hp[5], hp[6], hp[7]);
                    dofr[3] = mk8(lp[4], lp[5], lp[6], lp[7]);
                    if (w == 0) {
#pragma unroll
                        for (int j = 0; j < 4; ++j) {
                            DOT32[(8 * q + 2 * j) * 8 + c] = (hp[j] & 0xffffu) | (lp[j] << 16);
                            DOT32[(8 * q + 2 * j + 1) * 8 + c] = (hp[j] >> 16) | (lp[j] & 0xffff0000u);
                            DOT32[(32 + 8 * q + 2 * j) * 8 + c] = (hp[4 + j] & 0xffffu) | (lp[4 + j] << 16);
                            DOT32[(32 + 8 * q + 2 * j + 1) * 8 + c] = (hp[4 + j] >> 16) | (lp[4 + j] & 0xffff0000u);
                        }
                    }
                }
                acc = mm_rh(dofr, W2R, w, c, q);
                if (q < 2) {
                    int col = 16 * w + c;
                    float da[4];
#pragma unroll
                    for (int r = 0; r < 4; ++r) da[r] = acc[r] * gd_s[(4 * q + r) * 68 + col];
                    unsigned hp0, lp0, hp1, lp1;
                    cvt2pk(da[0], da[1], hp0, lp0);
                    cvt2pk(da[2], da[3], hp1, lp1);
                    u32x4 dt;
                    dt[0] = (hp0 & 0xffffu) | (lp0 << 16);
                    dt[1] = (hp0 >> 16) | (lp0 & 0xffff0000u);
                    dt[2] = (hp1 & 0xffffu) | (lp1 << 16);
                    dt[3] = (hp1 >> 16) | (lp1 & 0xffff0000u);
                    *(u32x4 *)&DAT32[col * 8 + 4 * q] = dt;
                }
                __syncthreads();
                // ---- update
                updW(KT32, DAT32, W1T, nullptr, w, c, q);
                updW(HT32, DOT32, W2T, W2R, w, c, q);
                if (tid8 < 64) {
                    u32x4 a0 = *(u32x4 *)&DAT32[tid8 * 8];
                    u32x4 a1 = *(u32x4 *)&DAT32[tid8 * 8 + 4];
                    u32x4 c0 = *(u32x4 *)&DOT32[tid8 * 8];
                    u32x4 c1 = *(u32x4 *)&DOT32[tid8 * 8 + 4];
                    float db1 = 0.f, db2 = 0.f, dlb = 0.f, dlg = 0.f;
#pragma unroll
                    for (int j = 0; j < 4; ++j) {
                        db1 += bf2f((short)(a0[j] & 0xffffu)) + bf2f((short)(a0[j] >> 16));
                        db1 += bf2f((short)(a1[j] & 0xffffu)) + bf2f((short)(a1[j] >> 16));
                        db2 += bf2f((short)(c0[j] & 0xffffu)) + bf2f((short)(c0[j] >> 16));
                        db2 += bf2f((short)(c1[j] & 0xffffu)) + bf2f((short)(c1[j] >> 16));
                    }
#pragma unroll
                    for (int b = 0; b < 8; ++b) {
                        float dzv2 = o_s[b * 68 + tid8];
                        dlb += dzv2;
                        dlg += dzv2 * xh_s[b * 68 + tid8];
                    }
                    lb_s[tid8] -= LR * dlb;
                    lg_s[tid8] -= LR * dlg;
                    b1_s[tid8] -= LR * db1;
                    b2_s[tid8] -= LR * db2;
                }
                __syncthreads();
            } else {
                // ---- final epilogue: double LN, out = q + z2, prefetch t+1
                float x0 = o_s[bb * 68 + j0], x1 = o_s[bb * 68 + j0 + 1];
                float mu = red32(x0 + x1) * (1.f / 64.f);
                float d0 = x0 - mu, d1 = x1 - mu;
                float var = red32(d0 * d0 + d1 * d1) * (1.f / 64.f);
                float rs = rsqrtf(var + 1e-5f);
                float z0 = d0 * rs * lg_s[j0] + lb_s[j0];
                float z1 = d1 * rs * lg_s[j0 + 1] + lb_s[j0 + 1];
                float mu2 = red32(z0 + z1) * (1.f / 64.f);
                float e0 = z0 - mu2, e1 = z1 - mu2;
                float var2 = red32(e0 * e0 + e1 * e1) * (1.f / 64.f);
                float rs2 = rsqrtf(var2 + 1e-5f);
                float z20 = e0 * rs2 * tG_s[j0] + tB_s[j0];
                float z21 = e1 * rs2 * tG_s[j0 + 1] + tB_s[j0 + 1];
                int idx = ((bb * Sv + t) * Hv + h) * Dv + j0;
                float2 ovv;
                ovv.x = pq.x + z20;
                ovv.y = pq.y + z21;
                *(float2 *)&out_g[idx] = ovv;
                if (t + 1 < Sv) {
                    int idx2 = ((bb * Sv + t + 1) * Hv + h) * Dv + j0;
                    pk = *(const float2 *)&k_g[idx2];
                    pv = *(const float2 *)&v_g[idx2];
                    pq = *(const float2 *)&q_g[idx2];
                }
                // no barrier: next prologue touches only Kp/KT32/tg_s
            }
        }
    }
}

// ---------------------------------------------------------------------------
// fp32 GEMM: C[M,N] = A[M,K] @ B[K,N]; mode 1: C = gelu(acc) * gate_ln
// ---------------------------------------------------------------------------
__global__ __launch_bounds__(256) void gemm_f32(
    const float *__restrict__ A, const float *__restrict__ B,
    float *__restrict__ C, const float *__restrict__ gate_ln,
    int M, int N, int K, int mode) {
    __shared__ float As[16][68];
    __shared__ float Bs[16][64];
    const int tid = threadIdx.x;
    const int tx = tid & 15, ty = tid >> 4;
    const int bm = blockIdx.y * 64, bn = blockIdx.x * 64;

    float acc[4][4] = {};
    for (int k0 = 0; k0 < K; k0 += 16) {
        {
            int r = tid >> 2, kk = (tid & 3) * 4;
            float4 av = *(const float4 *)(A + (long)(bm + r) * K + k0 + kk);
            As[kk + 0][r] = av.x;
            As[kk + 1][r] = av.y;
            As[kk + 2][r] = av.z;
            As[kk + 3][r] = av.w;
            int rr = tid >> 4, cc = (tid & 15) * 4;
            float4 bv = *(const float4 *)(B + (long)(k0 + rr) * N + bn + cc);
            *(float4 *)&Bs[rr][cc] = bv;
        }
        __syncthreads();
#pragma unroll
        for (int kk = 0; kk < 16; ++kk) {
            float4 a4 = *(float4 *)&As[kk][ty * 4];
            float4 b4 = *(float4 *)&Bs[kk][tx * 4];
            float a[4] = {a4.x, a4.y, a4.z, a4.w};
            float b[4] = {b4.x, b4.y, b4.z, b4.w};
#pragma unroll
            for (int i = 0; i < 4; ++i)
#pragma unroll
                for (int j = 0; j < 4; ++j) acc[i][j] += a[i] * b[j];
        }
        __syncthreads();
    }
#pragma unroll
    for (int i = 0; i < 4; ++i) {
        int row = bm + ty * 4 + i;
        float4 out;
        float v[4];
#pragma unroll
        for (int j = 0; j < 4; ++j) {
            float val = acc[i][j];
            if (mode == 1) {
                int col = bn + tx * 4 + j;
                val = gelu_f(val) * gate_ln[(long)row * N + col];
            }
            v[j] = val;
        }
        out.x = v[0]; out.y = v[1]; out.z = v[2]; out.w = v[3];
        *(float4 *)(C + (long)row * N + bn + tx * 4) = out;
    }
}

// ---------------------------------------------------------------------------
// Row LayerNorm over 1024
// ---------------------------------------------------------------------------
__global__ __launch_bounds__(256) void row_ln(const float *__restrict__ in,
                                              float *__restrict__ out,
                                              const float *__restrict__ g,
                                              const float *__restrict__ b) {
    __shared__ float sred[4], s2red[4];
    const int row = blockIdx.x;
    const int tid = threadIdx.x;
    const float *x = in + (long)row * 1024;
    float4 v = *(const float4 *)(x + tid * 4);
    float s = v.x + v.y + v.z + v.w;
    float s2 = v.x * v.x + v.y * v.y + v.z * v.z + v.w * v.w;
#pragma unroll
    for (int m = 1; m <= 32; m <<= 1) {
        s += __shfl_xor(s, m);
        s2 += __shfl_xor(s2, m);
    }
    if ((tid & 63) == 0) {
        sred[tid >> 6] = s;
        s2red[tid >> 6] = s2;
    }
    __syncthreads();
    float S = sred[0] + sred[1] + sred[2] + sred[3];
    float S2 = s2red[0] + s2red[1] + s2red[2] + s2red[3];
    float mu = S * (1.f / 1024.f);
    float var = S2 * (1.f / 1024.f) - mu * mu;
    float rs = rsqrtf(var + 1e-5f);
    float o[4] = {v.x, v.y, v.z, v.w};
    float4 ov;
    float r[4];
#pragma unroll
    for (int i = 0; i < 4; ++i) {
        int col = tid * 4 + i;
        r[i] = (o[i] - mu) * rs * g[col] + b[col];
    }
    ov.x = r[0]; ov.y = r[1]; ov.z = r[2]; ov.w = r[3];
    *(float4 *)(out + (long)row * 1024 + tid * 4) = ov;
}

// ---------------------------------------------------------------------------
// Launch
// ---------------------------------------------------------------------------
extern "C" void kernel_launch(void *const *d_in, const int *in_sizes, int n_in,
                              void *d_out, int out_size, void *d_ws,
                              size_t ws_size, hipStream_t stream) {
    const float *x = (const float *)d_in[0];
    const float *wq = (const float *)d_in[1];
    const float *wk = (const float *)d_in[2];
    const float *wv = (const float *)d_in[3];
    const float *fw_w1 = (const float *)d_in[4];
    const float *fw_b1 = (const float *)d_in[5];
    const float *fw_w2 = (const float *)d_in[6];
    const float *fw_b2 = (const float *)d_in[7];
    const float *fw_lng = (const float *)d_in[8];
    const float *fw_lnb = (const float *)d_in[9];
    const float *loss_w = (const float *)d_in[10];
    const float *loss_b = (const float *)d_in[11];
    const float *ttt_g = (const float *)d_in[12];
    const float *ttt_b = (const float *)d_in[13];
    const float *wo = (const float *)d_in[14];
    const float *wg = (const float *)d_in[15];
    const float *pn_g = (const float *)d_in[16];
    const float *pn_b = (const float *)d_in[17];

    const long MAT = 2048L * 1024L;
    float *q_ws = (float *)d_ws;
    float *k_ws = q_ws + MAT;
    float *v_ws = k_ws + MAT;
    float *out_ws = v_ws + MAT;
    float *ln_ws = k_ws;
    float *gated_ws = v_ws;

    dim3 gg(1024 / 64, 2048 / 64), bt(256);
    hipLaunchKernelGGL(gemm_f32, gg, bt, 0, stream, x, wq, q_ws,
                       (const float *)nullptr, 2048, 1024, 1024, 0);
    hipLaunchKernelGGL(gemm_f32, gg, bt, 0, stream, x, wk, k_ws,
                       (const float *)nullptr, 2048, 1024, 1024, 0);
    hipLaunchKernelGGL(gemm_f32, gg, bt, 0, stream, x, wv, v_ws,
                       (const float *)nullptr, 2048, 1024, 1024, 0);

    (void)hipFuncSetAttribute((const void *)ttt_scan,
                              hipFuncAttributeMaxDynamicSharedMemorySize,
                              LDS_BYTES);
    hipLaunchKernelGGL(ttt_scan, dim3(8), dim3(512), LDS_BYTES, stream,
                       q_ws, k_ws, v_ws, out_ws, fw_w1, fw_b1, fw_w2, fw_b2,
                       fw_lng, fw_lnb, loss_w, loss_b, ttt_g, ttt_b);

    hipLaunchKernelGGL(row_ln, dim3(2048), dim3(256), 0, stream, out_ws, ln_ws,
                       pn_g, pn_b);
    hipLaunchKernelGGL(gemm_f32, gg, bt, 0, stream, x, wg, gated_ws, ln_ws,
                       2048, 1024, 1024, 1);
    hipLaunchKernelGGL(gemm_f32, gg, bt, 0, stream, gated_ws, wo,
                       (float *)d_out, (const float *)nullptr, 2048, 1024,
                       1024, 0);
}

// Round 5
// 7695.025 us; speedup vs baseline: 1.2679x; 1.2679x over previous
//
#include <hip/hip_runtime.h>
#include <hip/hip_bf16.h>

// ---------------------------------------------------------------------------
// Problem constants
// ---------------------------------------------------------------------------
#define Bv 8
#define Sv 256
#define Hv 16
#define Dv 64
#define LR 0.1f
#define SCALE (2.0f / 8192.0f)   // dLoss/dpred scale: 2/(B*H*D)

using bf16x8 = __attribute__((ext_vector_type(8))) short;
using bf16x4 = __attribute__((ext_vector_type(4))) short;
using f32x4  = __attribute__((ext_vector_type(4))) float;
using u32x4  = __attribute__((ext_vector_type(4))) unsigned;
#define MFMA16(A, B, C) __builtin_amdgcn_mfma_f32_16x16x32_bf16(A, B, C, 0, 0, 0)

// ---------------------------------------------------------------------------
// LDS layout (single head / block). ushort offsets unless noted.
// Pitch-136 planes: hi[64]|lo[64]|pad[8]. W2R hi-only pitch 72.
// T-arrays packed u32 [dim][8]: dword = hi | lo<<16.
// ---------------------------------------------------------------------------
constexpr int U_W1T = 0;         // [f][d] 64x136
constexpr int U_W2T = 8704;      // [d][f] 64x136
constexpr int U_W2R = 17408;     // [f][d] 64x72 hi-only
constexpr int U_Kp  = 22016;     // 16x136
constexpr int U_Hp  = 24192;
constexpr int U_DPp = 26368;
constexpr int U_KT  = 28544;     // u32[64][8]
constexpr int U_HT  = 29568;
constexpr int U_DOT = 30592;
constexpr int U_DAT = 31616;
// float offsets
constexpr int F_O    = 16320;    // o / dz [8][68]
constexpr int F_XH   = 16864;
constexpr int F_GD   = 17408;
constexpr int F_TG   = 17952;
constexpr int F_B1   = 18496;
constexpr int F_B2   = 18560;
constexpr int F_LG   = 18624;
constexpr int F_LB   = 18688;
constexpr int F_LBV  = 18752;
constexpr int F_TGm  = 18816;
constexpr int F_TBm  = 18880;
constexpr int F_RSTD = 18944;    // [8]
constexpr int F_PS1  = 18952;    // [8][4]
constexpr int F_PS2  = 18984;    // [8][4]
constexpr int LDS_BYTES = 19016 * 4;   // 76064 B

// ---------------------------------------------------------------------------
// Helpers
// ---------------------------------------------------------------------------
__device__ __forceinline__ short bf_rn(float v) {
    unsigned u = __float_as_uint(v);
    unsigned r = u + 0x7fffu + ((u >> 16) & 1u);
    return (short)(r >> 16);
}
__device__ __forceinline__ void cvt1(float v, short &hi, short &lo) {
    hi = bf_rn(v);
    float hf = __uint_as_float(((unsigned)(unsigned short)hi) << 16);
    lo = bf_rn(v - hf);
}
__device__ __forceinline__ float bf2f(short u) {
    return __uint_as_float(((unsigned)(unsigned short)u) << 16);
}
__device__ __forceinline__ unsigned pkbf(float a, float b) {
    __hip_bfloat162 r = __float22bfloat162_rn(make_float2(a, b));
    unsigned u;
    __builtin_memcpy(&u, &r, sizeof(u));
    return u;
}
__device__ __forceinline__ void cvt2pk(float a, float b, unsigned &hp, unsigned &lp) {
    hp = pkbf(a, b);
    float ha = __uint_as_float(hp << 16);
    float hb = __uint_as_float(hp & 0xffff0000u);
    lp = pkbf(a - ha, b - hb);
}
__device__ __forceinline__ bf16x8 mk8(unsigned a, unsigned b, unsigned c, unsigned d) {
    union { unsigned u[4]; bf16x8 v; } x;
    x.u[0] = a; x.u[1] = b; x.u[2] = c; x.u[3] = d;
    return x.v;
}
__device__ __forceinline__ float red16(float v) {
    v += __shfl_xor(v, 1);
    v += __shfl_xor(v, 2);
    v += __shfl_xor(v, 4);
    v += __shfl_xor(v, 8);
    return v;
}
__device__ __forceinline__ float red32(float v) {
    v += __shfl_xor(v, 1); v += __shfl_xor(v, 2); v += __shfl_xor(v, 4);
    v += __shfl_xor(v, 8); v += __shfl_xor(v, 16);
    return v;
}
__device__ __forceinline__ float fast_tanh(float u) {
    u = fminf(fmaxf(u, -10.f), 10.f);
    float e = __expf(2.0f * u);
    return (e - 1.0f) / (e + 1.0f);
}
__device__ __forceinline__ void gelu_both(float x, float &g, float &dg) {
    const float C0 = 0.7978845608028654f, A0 = 0.044715f;
    float x2 = x * x;
    float u = C0 * x * (1.0f + A0 * x2);
    float t = fast_tanh(u);
    g = 0.5f * x * (1.0f + t);
    float du = C0 * (1.0f + 3.0f * A0 * x2);
    dg = 0.5f * (1.0f + t) + 0.5f * x * (1.0f - t * t) * du;
}
__device__ __forceinline__ float gelu_f(float x) {
    const float C0 = 0.7978845608028654f, A0 = 0.044715f;
    float u = C0 * x * (1.0f + A0 * x * x);
    return 0.5f * x * (1.0f + fast_tanh(u));
}

// ---- MFMA micro-kernels ---------------------------------------------------
// A from LDS planes, B fragments in registers (Bf[0]=bh0,[1]=bl0,[2]=bh1,[3]=bl1)
__device__ __forceinline__ f32x4 mm_lr(const unsigned short *Ap,
                                       const bf16x8 *Bf, int c, int q) {
    const unsigned short *ar = Ap + c * 136 + 8 * q;
    bf16x8 ah0 = *(const bf16x8 *)ar, al0 = *(const bf16x8 *)(ar + 64);
    bf16x8 ah1 = *(const bf16x8 *)(ar + 32), al1 = *(const bf16x8 *)(ar + 96);
    f32x4 x0 = {0.f, 0.f, 0.f, 0.f}, x1 = {0.f, 0.f, 0.f, 0.f};
    x0 = MFMA16(ah0, Bf[0], x0); x1 = MFMA16(ah1, Bf[2], x1);
    x0 = MFMA16(al0, Bf[0], x0); x1 = MFMA16(al1, Bf[2], x1);
    x0 = MFMA16(ah0, Bf[1], x0); x1 = MFMA16(ah1, Bf[3], x1);
    x0 = MFMA16(al0, Bf[1], x0); x1 = MFMA16(al1, Bf[3], x1);
    return x0 + x1;
}
// A and B fragments in registers
__device__ __forceinline__ f32x4 mm_rr(const bf16x8 *Af, const bf16x8 *Bf) {
    f32x4 x0 = {0.f, 0.f, 0.f, 0.f}, x1 = {0.f, 0.f, 0.f, 0.f};
    x0 = MFMA16(Af[0], Bf[0], x0); x1 = MFMA16(Af[2], Bf[2], x1);
    x0 = MFMA16(Af[1], Bf[0], x0); x1 = MFMA16(Af[3], Bf[2], x1);
    x0 = MFMA16(Af[0], Bf[1], x0); x1 = MFMA16(Af[2], Bf[3], x1);
    x0 = MFMA16(Af[1], Bf[1], x0); x1 = MFMA16(Af[3], Bf[3], x1);
    return x0 + x1;
}
// A frags in regs, B from hi-only LDS plane (gradient path)
__device__ __forceinline__ f32x4 mm_rh(const bf16x8 *Af,
                                       const unsigned short *BpHi,
                                       int w, int c, int q) {
    const unsigned short *br = BpHi + (16 * w + c) * 72 + 8 * q;
    bf16x8 bh0 = *(const bf16x8 *)br, bh1 = *(const bf16x8 *)(br + 32);
    f32x4 x0 = {0.f, 0.f, 0.f, 0.f}, x1 = {0.f, 0.f, 0.f, 0.f};
    x0 = MFMA16(Af[0], bh0, x0); x1 = MFMA16(Af[2], bh1, x1);
    x0 = MFMA16(Af[1], bh0, x0); x1 = MFMA16(Af[3], bh1, x1);
    return x0 + x1;
}

// W(col 16w+c) -= LR * X^T@Y ; X,Y packed-u32 T arrays [64][8].
__device__ __forceinline__ void updW(const unsigned *XT, const unsigned *YT,
                                     unsigned short *WT, unsigned short *WRh,
                                     int w, int c, int q) {
    bf16x8 zf = {0, 0, 0, 0, 0, 0, 0, 0};
    bf16x8 bh = zf, bl = zf;
    if (q == 0) {
        u32x4 y0 = *(const u32x4 *)&YT[(16 * w + c) * 8];
        u32x4 y1 = *(const u32x4 *)&YT[(16 * w + c) * 8 + 4];
#pragma unroll
        for (int j = 0; j < 4; ++j) {
            bh[j] = (short)(y0[j] & 0xffffu); bl[j] = (short)(y0[j] >> 16);
            bh[4 + j] = (short)(y1[j] & 0xffffu); bl[4 + j] = (short)(y1[j] >> 16);
        }
    }
#pragma unroll
    for (int mt = 0; mt < 4; ++mt) {
        bf16x8 ah = zf, al = zf;
        if (q == 0) {
            u32x4 x0 = *(const u32x4 *)&XT[(16 * mt + c) * 8];
            u32x4 x1 = *(const u32x4 *)&XT[(16 * mt + c) * 8 + 4];
#pragma unroll
            for (int j = 0; j < 4; ++j) {
                ah[j] = (short)(x0[j] & 0xffffu); al[j] = (short)(x0[j] >> 16);
                ah[4 + j] = (short)(x1[j] & 0xffffu); al[4 + j] = (short)(x1[j] >> 16);
            }
        }
        f32x4 g = {0.f, 0.f, 0.f, 0.f};
        g = MFMA16(ah, bh, g);
        g = MFMA16(al, bh, g);
        g = MFMA16(ah, bl, g);
        unsigned short *ph = &WT[(16 * w + c) * 136 + 16 * mt + 4 * q];
        unsigned short *pl = ph + 64;
        bf16x4 oh = *(bf16x4 *)ph, ol = *(bf16x4 *)pl, nh, nl;
#pragma unroll
        for (int r = 0; r < 4; ++r) {
            float wv = bf2f(oh[r]) + bf2f(ol[r]) - LR * g[r];
            short hh, ll;
            cvt1(wv, hh, ll);
            nh[r] = hh; nl[r] = ll;
            if (WRh) WRh[(16 * mt + 4 * q + r) * 72 + 16 * w + c] = (unsigned short)hh;
        }
        *(bf16x4 *)ph = nh;
        *(bf16x4 *)pl = nl;
    }
}

// ---------------------------------------------------------------------------
// TTT scan: 16 blocks x 256 threads, one head per block (private CU)
// ---------------------------------------------------------------------------
__global__ __launch_bounds__(256, 1) void ttt_scan(
    const float *__restrict__ q_g, const float *__restrict__ k_g,
    const float *__restrict__ v_g, float *__restrict__ out_g,
    const float *__restrict__ fw_w1, const float *__restrict__ fw_b1,
    const float *__restrict__ fw_w2, const float *__restrict__ fw_b2,
    const float *__restrict__ fw_lng, const float *__restrict__ fw_lnb,
    const float *__restrict__ loss_w, const float *__restrict__ loss_bv,
    const float *__restrict__ ttt_gv, const float *__restrict__ ttt_bv) {
    extern __shared__ char smem[];
    const int tid = threadIdx.x;
    const int h = blockIdx.x;
    const int w = tid >> 6, lane = tid & 63, c = lane & 15, q = lane >> 4;

    unsigned short *ub = (unsigned short *)smem;
    float *fbp = (float *)smem;
    unsigned short *W1T = ub + U_W1T, *W2T = ub + U_W2T, *W2R = ub + U_W2R;
    unsigned short *Kp = ub + U_Kp, *Hp = ub + U_Hp, *DPp = ub + U_DPp;
    unsigned *KT32 = (unsigned *)(ub + U_KT), *HT32 = (unsigned *)(ub + U_HT);
    unsigned *DOT32 = (unsigned *)(ub + U_DOT), *DAT32 = (unsigned *)(ub + U_DAT);
    float *o_s = fbp + F_O, *xh_s = fbp + F_XH, *gd_s = fbp + F_GD;
    float *tg_s = fbp + F_TG;
    float *b1_s = fbp + F_B1, *b2_s = fbp + F_B2, *lg_s = fbp + F_LG;
    float *lb_s = fbp + F_LB, *Lb_s = fbp + F_LBV;
    float *tG_s = fbp + F_TGm, *tB_s = fbp + F_TBm;
    float *rstd_s = fbp + F_RSTD, *ps1 = fbp + F_PS1, *ps2 = fbp + F_PS2;

    // ---- init weights into planes
    for (int i = tid; i < 4096; i += 256) {
        int r = i >> 6, cc = i & 63;
        short hi, lo;
        cvt1(fw_w1[h * 4096 + i], hi, lo);          // W1 [d=r][f=cc]
        W1T[cc * 136 + r] = (unsigned short)hi;
        W1T[cc * 136 + 64 + r] = (unsigned short)lo;
        cvt1(fw_w2[h * 4096 + i], hi, lo);          // W2 [f=r][d=cc]
        W2T[cc * 136 + r] = (unsigned short)hi;
        W2T[cc * 136 + 64 + r] = (unsigned short)lo;
        W2R[r * 72 + cc] = (unsigned short)hi;      // hi-only
    }
    // zero pad rows 8..15 of Kp/Hp/DPp (disjoint from param floats)
    for (int i = tid; i < 3 * 8 * 136; i += 256) {
        int a = i / (8 * 136), rem = i % (8 * 136);
        int r = 8 + rem / 136, u = rem % 136;
        (a == 0 ? Kp : a == 1 ? Hp : DPp)[r * 136 + u] = 0;
    }
    if (tid < 64) {
        b1_s[tid] = fw_b1[h * 64 + tid];
        b2_s[tid] = fw_b2[h * 64 + tid];
        lg_s[tid] = fw_lng[h * 64 + tid];
        lb_s[tid] = fw_lnb[h * 64 + tid];
        Lb_s[tid] = loss_bv[tid];
        tG_s[tid] = ttt_gv[h * 64 + tid];
        tB_s[tid] = ttt_bv[h * 64 + tid];
    }
    // ---- Lw fragments in registers (constant all kernel)
    bf16x8 LwTf[4], LwRf[4];
    {
        float tv[8];
        unsigned hp0, lp0, hp1, lp1, hp2, lp2, hp3, lp3;
#pragma unroll
        for (int j = 0; j < 8; ++j) tv[j] = loss_w[(8 * q + j) * 64 + 16 * w + c];
        cvt2pk(tv[0], tv[1], hp0, lp0); cvt2pk(tv[2], tv[3], hp1, lp1);
        cvt2pk(tv[4], tv[5], hp2, lp2); cvt2pk(tv[6], tv[7], hp3, lp3);
        LwTf[0] = mk8(hp0, hp1, hp2, hp3); LwTf[1] = mk8(lp0, lp1, lp2, lp3);
#pragma unroll
        for (int j = 0; j < 8; ++j) tv[j] = loss_w[(32 + 8 * q + j) * 64 + 16 * w + c];
        cvt2pk(tv[0], tv[1], hp0, lp0); cvt2pk(tv[2], tv[3], hp1, lp1);
        cvt2pk(tv[4], tv[5], hp2, lp2); cvt2pk(tv[6], tv[7], hp3, lp3);
        LwTf[2] = mk8(hp0, hp1, hp2, hp3); LwTf[3] = mk8(lp0, lp1, lp2, lp3);
        float4 ra = *(const float4 *)&loss_w[(16 * w + c) * 64 + 8 * q];
        float4 rb = *(const float4 *)&loss_w[(16 * w + c) * 64 + 8 * q + 4];
        cvt2pk(ra.x, ra.y, hp0, lp0); cvt2pk(ra.z, ra.w, hp1, lp1);
        cvt2pk(rb.x, rb.y, hp2, lp2); cvt2pk(rb.z, rb.w, hp3, lp3);
        LwRf[0] = mk8(hp0, hp1, hp2, hp3); LwRf[1] = mk8(lp0, lp1, lp2, lp3);
        ra = *(const float4 *)&loss_w[(16 * w + c) * 64 + 32 + 8 * q];
        rb = *(const float4 *)&loss_w[(16 * w + c) * 64 + 32 + 8 * q + 4];
        cvt2pk(ra.x, ra.y, hp0, lp0); cvt2pk(ra.z, ra.w, hp1, lp1);
        cvt2pk(rb.x, rb.y, hp2, lp2); cvt2pk(rb.z, rb.w, hp3, lp3);
        LwRf[2] = mk8(hp0, hp1, hp2, hp3); LwRf[3] = mk8(lp0, lp1, lp2, lp3);
    }
    __syncthreads();

    // ---- W1/W2 B-fragments in registers. Wave w's mm needs rows 16w+c of
    // W1T/W2T, and updW's wave w writes exactly those rows — so each wave
    // refreshes its own frags after its updW (same-wave LDS ordering).
    bf16x8 w1f[4], w2f[4];
    {
        const unsigned short *r1 = W1T + (16 * w + c) * 136 + 8 * q;
        w1f[0] = *(const bf16x8 *)r1;        w1f[1] = *(const bf16x8 *)(r1 + 64);
        w1f[2] = *(const bf16x8 *)(r1 + 32); w1f[3] = *(const bf16x8 *)(r1 + 96);
        const unsigned short *r2 = W2T + (16 * w + c) * 136 + 8 * q;
        w2f[0] = *(const bf16x8 *)r2;        w2f[1] = *(const bf16x8 *)(r2 + 64);
        w2f[2] = *(const bf16x8 *)(r2 + 32); w2f[3] = *(const bf16x8 *)(r2 + 96);
    }

    const int bb = tid >> 5, j0 = (tid & 31) * 2;
    float2 pk, pv, pq;
    {
        int idx = ((bb * Sv + 0) * Hv + h) * Dv + j0;
        pk = *(const float2 *)&k_g[idx];
        pv = *(const float2 *)&v_g[idx];
        pq = *(const float2 *)&q_g[idx];
    }

#pragma unroll 1
    for (int t = 0; t < Sv; ++t) {
        // ---- prologue: stage k planes + KT32 + tg
        {
            unsigned hp, lp;
            cvt2pk(pk.x, pk.y, hp, lp);
            *(unsigned *)&Kp[bb * 136 + j0] = hp;
            *(unsigned *)&Kp[bb * 136 + 64 + j0] = lp;
            KT32[j0 * 8 + bb] = (hp & 0xffffu) | (lp << 16);
            KT32[(j0 + 1) * 8 + bb] = (hp >> 16) | (lp & 0xffff0000u);
            tg_s[bb * 68 + j0] = pv.x - pk.x;
            tg_s[bb * 68 + j0 + 1] = pv.y - pk.y;
        }
        __syncthreads();

#pragma unroll 1
        for (int step = 0; step < 5; ++step) {
            // ---- F1: h = gelu(k@W1 + b1)   (B from regs)
            f32x4 acc = mm_lr(Kp, w1f, c, q);
            if (q < 2) {
                float bias = b1_s[16 * w + c];
                float g[4], dg[4];
#pragma unroll
                for (int r = 0; r < 4; ++r) gelu_both(acc[r] + bias, g[r], dg[r]);
                unsigned hp0, lp0, hp1, lp1;
                cvt2pk(g[0], g[1], hp0, lp0);
                cvt2pk(g[2], g[3], hp1, lp1);
                int col = 16 * w + c;
                Hp[(4 * q + 0) * 136 + col] = (unsigned short)(hp0 & 0xffffu);
                Hp[(4 * q + 1) * 136 + col] = (unsigned short)(hp0 >> 16);
                Hp[(4 * q + 2) * 136 + col] = (unsigned short)(hp1 & 0xffffu);
                Hp[(4 * q + 3) * 136 + col] = (unsigned short)(hp1 >> 16);
                Hp[(4 * q + 0) * 136 + 64 + col] = (unsigned short)(lp0 & 0xffffu);
                Hp[(4 * q + 1) * 136 + 64 + col] = (unsigned short)(lp0 >> 16);
                Hp[(4 * q + 2) * 136 + 64 + col] = (unsigned short)(lp1 & 0xffffu);
                Hp[(4 * q + 3) * 136 + 64 + col] = (unsigned short)(lp1 >> 16);
                u32x4 ht;
                ht[0] = (hp0 & 0xffffu) | (lp0 << 16);
                ht[1] = (hp0 >> 16) | (lp0 & 0xffff0000u);
                ht[2] = (hp1 & 0xffffu) | (lp1 << 16);
                ht[3] = (hp1 >> 16) | (lp1 & 0xffff0000u);
                *(u32x4 *)&HT32[col * 8 + 4 * q] = ht;
#pragma unroll
                for (int r = 0; r < 4; ++r) gd_s[(4 * q + r) * 68 + col] = dg[r];
            }
            __syncthreads();
            // ---- F2: o = h@W2 + b2 ; partial row sums   (B from regs)
            acc = mm_lr(Hp, w2f, c, q);
            if (q < 2) {
                float bias = b2_s[16 * w + c];
#pragma unroll
                for (int r = 0; r < 4; ++r) {
                    float ov = acc[r] + bias;
                    o_s[(4 * q + r) * 68 + 16 * w + c] = ov;
                    float sv = red16(ov), sq = red16(ov * ov);
                    if (c == 0) {
                        ps1[(4 * q + r) * 4 + w] = sv;
                        ps2[(4 * q + r) * 4 + w] = sq;
                    }
                }
            }
            __syncthreads();

            if (step < 4) {
                // ---- F3: LN-apply in regs -> mm_rr vs LwT frags
                bf16x8 zfr[4] = {{0,0,0,0,0,0,0,0},{0,0,0,0,0,0,0,0},
                                 {0,0,0,0,0,0,0,0},{0,0,0,0,0,0,0,0}};
                if (c < 8) {
                    float4 p1 = *(float4 *)&ps1[c * 4];
                    float4 p2 = *(float4 *)&ps2[c * 4];
                    float mu = (p1.x + p1.y + p1.z + p1.w) * (1.f / 64.f);
                    float ms = (p2.x + p2.y + p2.z + p2.w) * (1.f / 64.f);
                    float rs = rsqrtf(ms - mu * mu + 1e-5f);
                    float4 oa = *(float4 *)&o_s[c * 68 + 8 * q];
                    float4 ob = *(float4 *)&o_s[c * 68 + 8 * q + 4];
                    float4 oc = *(float4 *)&o_s[c * 68 + 32 + 8 * q];
                    float4 od = *(float4 *)&o_s[c * 68 + 32 + 8 * q + 4];
                    float4 ga = *(float4 *)&lg_s[8 * q];
                    float4 gb = *(float4 *)&lg_s[8 * q + 4];
                    float4 gc = *(float4 *)&lg_s[32 + 8 * q];
                    float4 ge = *(float4 *)&lg_s[32 + 8 * q + 4];
                    float4 ba = *(float4 *)&lb_s[8 * q];
                    float4 bbv = *(float4 *)&lb_s[8 * q + 4];
                    float4 bc = *(float4 *)&lb_s[32 + 8 * q];
                    float4 be = *(float4 *)&lb_s[32 + 8 * q + 4];
                    float xh[16], z[16];
                    float ov[16] = {oa.x, oa.y, oa.z, oa.w, ob.x, ob.y, ob.z, ob.w,
                                    oc.x, oc.y, oc.z, oc.w, od.x, od.y, od.z, od.w};
                    float gv[16] = {ga.x, ga.y, ga.z, ga.w, gb.x, gb.y, gb.z, gb.w,
                                    gc.x, gc.y, gc.z, gc.w, ge.x, ge.y, ge.z, ge.w};
                    float bv[16] = {ba.x, ba.y, ba.z, ba.w, bbv.x, bbv.y, bbv.z, bbv.w,
                                    bc.x, bc.y, bc.z, bc.w, be.x, be.y, be.z, be.w};
#pragma unroll
                    for (int j = 0; j < 16; ++j) {
                        xh[j] = (ov[j] - mu) * rs;
                        z[j] = xh[j] * gv[j] + bv[j];
                    }
                    unsigned hp[8], lp[8];
#pragma unroll
                    for (int j = 0; j < 8; ++j) cvt2pk(z[2 * j], z[2 * j + 1], hp[j], lp[j]);
                    zfr[0] = mk8(hp[0], hp[1], hp[2], hp[3]);
                    zfr[1] = mk8(lp[0], lp[1], lp[2], lp[3]);
                    zfr[2] = mk8(hp[4], hp[5], hp[6], hp[7]);
                    zfr[3] = mk8(lp[4], lp[5], lp[6], lp[7]);
                    if (w == 0) {
                        *(float4 *)&xh_s[c * 68 + 8 * q] = make_float4(xh[0], xh[1], xh[2], xh[3]);
                        *(float4 *)&xh_s[c * 68 + 8 * q + 4] = make_float4(xh[4], xh[5], xh[6], xh[7]);
                        *(float4 *)&xh_s[c * 68 + 32 + 8 * q] = make_float4(xh[8], xh[9], xh[10], xh[11]);
                        *(float4 *)&xh_s[c * 68 + 32 + 8 * q + 4] = make_float4(xh[12], xh[13], xh[14], xh[15]);
                        if (q == 0) rstd_s[c] = rs;
                    }
                }
                acc = mm_rr(zfr, LwTf);
                if (q < 2) {
                    int col = 16 * w + c;
                    float dp[4];
#pragma unroll
                    for (int r = 0; r < 4; ++r)
                        dp[r] = (acc[r] + Lb_s[col] - tg_s[(4 * q + r) * 68 + col]) * SCALE;
                    unsigned hp0, lp0, hp1, lp1;
                    cvt2pk(dp[0], dp[1], hp0, lp0);
                    cvt2pk(dp[2], dp[3], hp1, lp1);
                    DPp[(4 * q + 0) * 136 + col] = (unsigned short)(hp0 & 0xffffu);
                    DPp[(4 * q + 1) * 136 + col] = (unsigned short)(hp0 >> 16);
                    DPp[(4 * q + 2) * 136 + col] = (unsigned short)(hp1 & 0xffffu);
                    DPp[(4 * q + 3) * 136 + col] = (unsigned short)(hp1 >> 16);
                    DPp[(4 * q + 0) * 136 + 64 + col] = (unsigned short)(lp0 & 0xffffu);
                    DPp[(4 * q + 1) * 136 + 64 + col] = (unsigned short)(lp0 >> 16);
                    DPp[(4 * q + 2) * 136 + 64 + col] = (unsigned short)(lp1 & 0xffffu);
                    DPp[(4 * q + 3) * 136 + 64 + col] = (unsigned short)(lp1 >> 16);
                }
                __syncthreads();
                // ---- B1: dz = dp @ Lw^T ; LNb partial sums
                acc = mm_lr(DPp, LwRf, c, q);
                if (q < 2) {
                    float lgc = lg_s[16 * w + c];
#pragma unroll
                    for (int r = 0; r < 4; ++r) {
                        float dz = acc[r];
                        o_s[(4 * q + r) * 68 + 16 * w + c] = dz;
                        float xv = xh_s[(4 * q + r) * 68 + 16 * w + c];
                        float d1 = dz * lgc;
                        float s1 = red16(d1), s2 = red16(d1 * xv);
                        if (c == 0) {
                            ps1[(4 * q + r) * 4 + w] = s1;
                            ps2[(4 * q + r) * 4 + w] = s2;
                        }
                    }
                }
                __syncthreads();
                // ---- B2: LNb-apply in regs -> mm_rh vs W2R-hi
                bf16x8 dofr[4] = {{0,0,0,0,0,0,0,0},{0,0,0,0,0,0,0,0},
                                  {0,0,0,0,0,0,0,0},{0,0,0,0,0,0,0,0}};
                if (c < 8) {
                    float4 p1 = *(float4 *)&ps1[c * 4];
                    float4 p2 = *(float4 *)&ps2[c * 4];
                    float S1 = (p1.x + p1.y + p1.z + p1.w) * (1.f / 64.f);
                    float S2 = (p2.x + p2.y + p2.z + p2.w) * (1.f / 64.f);
                    float rs = rstd_s[c];
                    float4 za = *(float4 *)&o_s[c * 68 + 8 * q];
                    float4 zb = *(float4 *)&o_s[c * 68 + 8 * q + 4];
                    float4 zc = *(float4 *)&o_s[c * 68 + 32 + 8 * q];
                    float4 zd = *(float4 *)&o_s[c * 68 + 32 + 8 * q + 4];
                    float4 xa = *(float4 *)&xh_s[c * 68 + 8 * q];
                    float4 xb = *(float4 *)&xh_s[c * 68 + 8 * q + 4];
                    float4 xc = *(float4 *)&xh_s[c * 68 + 32 + 8 * q];
                    float4 xd = *(float4 *)&xh_s[c * 68 + 32 + 8 * q + 4];
                    float4 ga = *(float4 *)&lg_s[8 * q];
                    float4 gb = *(float4 *)&lg_s[8 * q + 4];
                    float4 gc = *(float4 *)&lg_s[32 + 8 * q];
                    float4 ge = *(float4 *)&lg_s[32 + 8 * q + 4];
                    float dzv[16] = {za.x, za.y, za.z, za.w, zb.x, zb.y, zb.z, zb.w,
                                     zc.x, zc.y, zc.z, zc.w, zd.x, zd.y, zd.z, zd.w};
                    float xv[16] = {xa.x, xa.y, xa.z, xa.w, xb.x, xb.y, xb.z, xb.w,
                                    xc.x, xc.y, xc.z, xc.w, xd.x, xd.y, xd.z, xd.w};
                    float gv[16] = {ga.x, ga.y, ga.z, ga.w, gb.x, gb.y, gb.z, gb.w,
                                    gc.x, gc.y, gc.z, gc.w, ge.x, ge.y, ge.z, ge.w};
                    float dov[16];
#pragma unroll
                    for (int j = 0; j < 16; ++j)
                        dov[j] = rs * (dzv[j] * gv[j] - S1 - xv[j] * S2);
                    unsigned hp[8], lp[8];
#pragma unroll
                    for (int j = 0; j < 8; ++j) cvt2pk(dov[2 * j], dov[2 * j + 1], hp[j], lp[j]);
                    dofr[0] = mk8(hp[0], hp[1], hp[2], hp[3]);
                    dofr[1] = mk8(lp[0], lp[1], lp[2], lp[3]);
                    dofr[2] = mk8(hp[4], hp[5], hp[6], hp[7]);
                    dofr[3] = mk8(lp[4], lp[5], lp[6], lp[7]);
                    if (w == 0) {
#pragma unroll
                        for (int j = 0; j < 4; ++j) {
                            DOT32[(8 * q + 2 * j) * 8 + c] = (hp[j] & 0xffffu) | (lp[j] << 16);
                            DOT32[(8 * q + 2 * j + 1) * 8 + c] = (hp[j] >> 16) | (lp[j] & 0xffff0000u);
                            DOT32[(32 + 8 * q + 2 * j) * 8 + c] = (hp[4 + j] & 0xffffu) | (lp[4 + j] << 16);
                            DOT32[(32 + 8 * q + 2 * j + 1) * 8 + c] = (hp[4 + j] >> 16) | (lp[4 + j] & 0xffff0000u);
                        }
                    }
                }
                acc = mm_rh(dofr, W2R, w, c, q);
                if (q < 2) {
                    int col = 16 * w + c;
                    float da[4];
#pragma unroll
                    for (int r = 0; r < 4; ++r) da[r] = acc[r] * gd_s[(4 * q + r) * 68 + col];
                    unsigned hp0, lp0, hp1, lp1;
                    cvt2pk(da[0], da[1], hp0, lp0);
                    cvt2pk(da[2], da[3], hp1, lp1);
                    u32x4 dt;
                    dt[0] = (hp0 & 0xffffu) | (lp0 << 16);
                    dt[1] = (hp0 >> 16) | (lp0 & 0xffff0000u);
                    dt[2] = (hp1 & 0xffffu) | (lp1 << 16);
                    dt[3] = (hp1 >> 16) | (lp1 & 0xffff0000u);
                    *(u32x4 *)&DAT32[col * 8 + 4 * q] = dt;
                }
                __syncthreads();
                // ---- update weights + vector params
                updW(KT32, DAT32, W1T, nullptr, w, c, q);
                updW(HT32, DOT32, W2T, W2R, w, c, q);
                // refresh register B-frags from self-written rows
                {
                    const unsigned short *r1 = W1T + (16 * w + c) * 136 + 8 * q;
                    w1f[0] = *(const bf16x8 *)r1;        w1f[1] = *(const bf16x8 *)(r1 + 64);
                    w1f[2] = *(const bf16x8 *)(r1 + 32); w1f[3] = *(const bf16x8 *)(r1 + 96);
                    const unsigned short *r2 = W2T + (16 * w + c) * 136 + 8 * q;
                    w2f[0] = *(const bf16x8 *)r2;        w2f[1] = *(const bf16x8 *)(r2 + 64);
                    w2f[2] = *(const bf16x8 *)(r2 + 32); w2f[3] = *(const bf16x8 *)(r2 + 96);
                }
                if (tid < 64) {
                    u32x4 a0 = *(u32x4 *)&DAT32[tid * 8];
                    u32x4 a1 = *(u32x4 *)&DAT32[tid * 8 + 4];
                    u32x4 c0 = *(u32x4 *)&DOT32[tid * 8];
                    u32x4 c1 = *(u32x4 *)&DOT32[tid * 8 + 4];
                    float db1 = 0.f, db2 = 0.f, dlb = 0.f, dlg = 0.f;
#pragma unroll
                    for (int j = 0; j < 4; ++j) {
                        db1 += bf2f((short)(a0[j] & 0xffffu)) + bf2f((short)(a0[j] >> 16));
                        db1 += bf2f((short)(a1[j] & 0xffffu)) + bf2f((short)(a1[j] >> 16));
                        db2 += bf2f((short)(c0[j] & 0xffffu)) + bf2f((short)(c0[j] >> 16));
                        db2 += bf2f((short)(c1[j] & 0xffffu)) + bf2f((short)(c1[j] >> 16));
                    }
#pragma unroll
                    for (int b = 0; b < 8; ++b) {
                        float dzv2 = o_s[b * 68 + tid];
                        dlb += dzv2;
                        dlg += dzv2 * xh_s[b * 68 + tid];
                    }
                    lb_s[tid] -= LR * dlb;
                    lg_s[tid] -= LR * dlg;
                    b1_s[tid] -= LR * db1;
                    b2_s[tid] -= LR * db2;
                }
                __syncthreads();
            } else {
                // ---- final epilogue: double LN, out = q + z2, prefetch t+1
                float x0 = o_s[bb * 68 + j0], x1 = o_s[bb * 68 + j0 + 1];
                float mu = red32(x0 + x1) * (1.f / 64.f);
                float d0 = x0 - mu, d1 = x1 - mu;
                float var = red32(d0 * d0 + d1 * d1) * (1.f / 64.f);
                float rs = rsqrtf(var + 1e-5f);
                float z0 = d0 * rs * lg_s[j0] + lb_s[j0];
                float z1 = d1 * rs * lg_s[j0 + 1] + lb_s[j0 + 1];
                float mu2 = red32(z0 + z1) * (1.f / 64.f);
                float e0 = z0 - mu2, e1 = z1 - mu2;
                float var2 = red32(e0 * e0 + e1 * e1) * (1.f / 64.f);
                float rs2 = rsqrtf(var2 + 1e-5f);
                float z20 = e0 * rs2 * tG_s[j0] + tB_s[j0];
                float z21 = e1 * rs2 * tG_s[j0 + 1] + tB_s[j0 + 1];
                int idx = ((bb * Sv + t) * Hv + h) * Dv + j0;
                float2 ovv;
                ovv.x = pq.x + z20;
                ovv.y = pq.y + z21;
                *(float2 *)&out_g[idx] = ovv;
                if (t + 1 < Sv) {
                    int idx2 = ((bb * Sv + t + 1) * Hv + h) * Dv + j0;
                    pk = *(const float2 *)&k_g[idx2];
                    pv = *(const float2 *)&v_g[idx2];
                    pq = *(const float2 *)&q_g[idx2];
                }
                // no barrier: next prologue touches only Kp/KT32/tg_s
            }
        }
    }
}

// ---------------------------------------------------------------------------
// fp32 GEMM: C[M,N] = A[M,K] @ B[K,N]; mode 1: C = gelu(acc) * gate_ln
// ---------------------------------------------------------------------------
__global__ __launch_bounds__(256) void gemm_f32(
    const float *__restrict__ A, const float *__restrict__ B,
    float *__restrict__ C, const float *__restrict__ gate_ln,
    int M, int N, int K, int mode) {
    __shared__ float As[16][68];
    __shared__ float Bs[16][64];
    const int tid = threadIdx.x;
    const int tx = tid & 15, ty = tid >> 4;
    const int bm = blockIdx.y * 64, bn = blockIdx.x * 64;

    float acc[4][4] = {};
    for (int k0 = 0; k0 < K; k0 += 16) {
        {
            int r = tid >> 2, kk = (tid & 3) * 4;
            float4 av = *(const float4 *)(A + (long)(bm + r) * K + k0 + kk);
            As[kk + 0][r] = av.x;
            As[kk + 1][r] = av.y;
            As[kk + 2][r] = av.z;
            As[kk + 3][r] = av.w;
            int rr = tid >> 4, cc = (tid & 15) * 4;
            float4 bv = *(const float4 *)(B + (long)(k0 + rr) * N + bn + cc);
            *(float4 *)&Bs[rr][cc] = bv;
        }
        __syncthreads();
#pragma unroll
        for (int kk = 0; kk < 16; ++kk) {
            float4 a4 = *(float4 *)&As[kk][ty * 4];
            float4 b4 = *(float4 *)&Bs[kk][tx * 4];
            float a[4] = {a4.x, a4.y, a4.z, a4.w};
            float b[4] = {b4.x, b4.y, b4.z, b4.w};
#pragma unroll
            for (int i = 0; i < 4; ++i)
#pragma unroll
                for (int j = 0; j < 4; ++j) acc[i][j] += a[i] * b[j];
        }
        __syncthreads();
    }
#pragma unroll
    for (int i = 0; i < 4; ++i) {
        int row = bm + ty * 4 + i;
        float4 out;
        float v[4];
#pragma unroll
        for (int j = 0; j < 4; ++j) {
            float val = acc[i][j];
            if (mode == 1) {
                int col = bn + tx * 4 + j;
                val = gelu_f(val) * gate_ln[(long)row * N + col];
            }
            v[j] = val;
        }
        out.x = v[0]; out.y = v[1]; out.z = v[2]; out.w = v[3];
        *(float4 *)(C + (long)row * N + bn + tx * 4) = out;
    }
}

// ---------------------------------------------------------------------------
// Row LayerNorm over 1024
// ---------------------------------------------------------------------------
__global__ __launch_bounds__(256) void row_ln(const float *__restrict__ in,
                                              float *__restrict__ out,
                                              const float *__restrict__ g,
                                              const float *__restrict__ b) {
    __shared__ float sred[4], s2red[4];
    const int row = blockIdx.x;
    const int tid = threadIdx.x;
    const float *x = in + (long)row * 1024;
    float4 v = *(const float4 *)(x + tid * 4);
    float s = v.x + v.y + v.z + v.w;
    float s2 = v.x * v.x + v.y * v.y + v.z * v.z + v.w * v.w;
#pragma unroll
    for (int m = 1; m <= 32; m <<= 1) {
        s += __shfl_xor(s, m);
        s2 += __shfl_xor(s2, m);
    }
    if ((tid & 63) == 0) {
        sred[tid >> 6] = s;
        s2red[tid >> 6] = s2;
    }
    __syncthreads();
    float S = sred[0] + sred[1] + sred[2] + sred[3];
    float S2 = s2red[0] + s2red[1] + s2red[2] + s2red[3];
    float mu = S * (1.f / 1024.f);
    float var = S2 * (1.f / 1024.f) - mu * mu;
    float rs = rsqrtf(var + 1e-5f);
    float o[4] = {v.x, v.y, v.z, v.w};
    float4 ov;
    float r[4];
#pragma unroll
    for (int i = 0; i < 4; ++i) {
        int col = tid * 4 + i;
        r[i] = (o[i] - mu) * rs * g[col] + b[col];
    }
    ov.x = r[0]; ov.y = r[1]; ov.z = r[2]; ov.w = r[3];
    *(float4 *)(out + (long)row * 1024 + tid * 4) = ov;
}

// ---------------------------------------------------------------------------
// Launch
// ---------------------------------------------------------------------------
extern "C" void kernel_launch(void *const *d_in, const int *in_sizes, int n_in,
                              void *d_out, int out_size, void *d_ws,
                              size_t ws_size, hipStream_t stream) {
    const float *x = (const float *)d_in[0];
    const float *wq = (const float *)d_in[1];
    const float *wk = (const float *)d_in[2];
    const float *wv = (const float *)d_in[3];
    const float *fw_w1 = (const float *)d_in[4];
    const float *fw_b1 = (const float *)d_in[5];
    const float *fw_w2 = (const float *)d_in[6];
    const float *fw_b2 = (const float *)d_in[7];
    const float *fw_lng = (const float *)d_in[8];
    const float *fw_lnb = (const float *)d_in[9];
    const float *loss_w = (const float *)d_in[10];
    const float *loss_b = (const float *)d_in[11];
    const float *ttt_g = (const float *)d_in[12];
    const float *ttt_b = (const float *)d_in[13];
    const float *wo = (const float *)d_in[14];
    const float *wg = (const float *)d_in[15];
    const float *pn_g = (const float *)d_in[16];
    const float *pn_b = (const float *)d_in[17];

    const long MAT = 2048L * 1024L;
    float *q_ws = (float *)d_ws;
    float *k_ws = q_ws + MAT;
    float *v_ws = k_ws + MAT;
    float *out_ws = v_ws + MAT;
    float *ln_ws = k_ws;
    float *gated_ws = v_ws;

    dim3 gg(1024 / 64, 2048 / 64), bt(256);
    hipLaunchKernelGGL(gemm_f32, gg, bt, 0, stream, x, wq, q_ws,
                       (const float *)nullptr, 2048, 1024, 1024, 0);
    hipLaunchKernelGGL(gemm_f32, gg, bt, 0, stream, x, wk, k_ws,
                       (const float *)nullptr, 2048, 1024, 1024, 0);
    hipLaunchKernelGGL(gemm_f32, gg, bt, 0, stream, x, wv, v_ws,
                       (const float *)nullptr, 2048, 1024, 1024, 0);

    (void)hipFuncSetAttribute((const void *)ttt_scan,
                              hipFuncAttributeMaxDynamicSharedMemorySize,
                              LDS_BYTES);
    hipLaunchKernelGGL(ttt_scan, dim3(16), dim3(256), LDS_BYTES, stream,
                       q_ws, k_ws, v_ws, out_ws, fw_w1, fw_b1, fw_w2, fw_b2,
                       fw_lng, fw_lnb, loss_w, loss_b, ttt_g, ttt_b);

    hipLaunchKernelGGL(row_ln, dim3(2048), dim3(256), 0, stream, out_ws, ln_ws,
                       pn_g, pn_b);
    hipLaunchKernelGGL(gemm_f32, gg, bt, 0, stream, x, wg, gated_ws, ln_ws,
                       2048, 1024, 1024, 1);
    hipLaunchKernelGGL(gemm_f32, gg, bt, 0, stream, gated_ws, wo,
                       (float *)d_out, (const float *)nullptr, 2048, 1024,
                       1024, 0);
}